// Round 2
// baseline (785.044 us; speedup 1.0000x reference)
//
#include <hip/hip_runtime.h>

#define NSHOTS 4
#define NT     512
#define NZ     256
#define NX     256
#define NRECS  128

static constexpr float DTf    = 0.001f;
static constexpr float INVDH2 = 1.0f / (10.0f * 10.0f);

#define KSTEPS 16                 // fused time steps per phase
#define TILE   32                 // interior tile edge
#define EXT    64                 // TILE + 2*KSTEPS
#define RPT    8                  // ext rows per thread
#define NWAVES 8
#define BLOCK  512
#define NWG    (NSHOTS * 8 * 8)   // 256 workgroups, all co-resident
#define NPHASE (NT / KSTEPS)      // 32

// lane i <- lane i-1 (left x-neighbor); lane 0 gets 0 (matches zero pad)
__device__ __forceinline__ float nbr_left(float v) {
  return __int_as_float(__builtin_amdgcn_update_dpp(
      0, __float_as_int(v), 0x138 /*WAVE_SHR1*/, 0xf, 0xf, false));
}
// lane i <- lane i+1 (right x-neighbor); lane 63 gets 0
__device__ __forceinline__ float nbr_right(float v) {
  return __int_as_float(__builtin_amdgcn_update_dpp(
      0, __float_as_int(v), 0x130 /*WAVE_SHL1*/, 0xf, 0xf, false));
}

// Single persistent-style kernel: 32 ghost-zone phases x 16 steps, with a
// device-scope grid barrier between phases. 256 WGs (1 per 32x32 interior
// tile per shot); capacity 2 blocks/CU => all co-resident, no deadlock.
__global__ __launch_bounds__(BLOCK, 4) void wave_all(
    float* __restrict__ f0c, float* __restrict__ f0p,   // pair 0 (written on even phases)
    float* __restrict__ f1c, float* __restrict__ f1p,   // pair 1 (written on odd phases)
    const float* __restrict__ vp,
    const float* __restrict__ xwav,
    const int* __restrict__ src_z, const int* __restrict__ src_x,
    const int* __restrict__ rec_z, const int* __restrict__ rec_x,
    float* __restrict__ out,                            // [NSHOTS*NT*NRECS]
    unsigned* __restrict__ ctr)                         // zeroed before launch
{
  const int bid  = blockIdx.x;
  const int s    = bid >> 6;
  const int tz   = (bid >> 3) & 7;
  const int tx   = bid & 7;
  const int tid  = threadIdx.x;
  const int w    = tid >> 6;     // wave -> z strip
  const int lane = tid & 63;     // x within ext region

  const int gz0 = tz * TILE - KSTEPS;
  const int gx0 = tx * TILE - KSTEPS;
  const int gx  = gx0 + lane;
  const int zb  = w * RPT;

  __shared__ float haloTop[2][NWAVES][64];
  __shared__ float haloBot[2][NWAVES][64];
  __shared__ float recTile[2][TILE][TILE + 1];
  __shared__ int   nRecS;
  __shared__ short recR[NRECS], recZL[NRECS], recXL[NRECS];

  // Receiver compaction — once for all 512 steps.
  if (tid == 0) nRecS = 0;
  __syncthreads();
  if (tid < NRECS) {
    const int rz = rec_z[s * NRECS + tid];
    const int rx = rec_x[s * NRECS + tid];
    const int lz = rz - tz * TILE;
    const int lx = rx - tx * TILE;
    if ((unsigned)lz < (unsigned)TILE && (unsigned)lx < (unsigned)TILE) {
      const int k = atomicAdd(&nRecS, 1);
      recR[k] = (short)tid; recZL[k] = (short)lz; recXL[k] = (short)lx;
    }
  }
  __syncthreads();
  const int nRec = nRecS;

  // Source ownership (ext-region coverage keeps halo values valid).
  const int slz = src_z[s] - gz0;
  const int slx = src_x[s] - gx0;
  const bool srcMine = (slx == lane) && ((unsigned)(slz - zb) < (unsigned)RPT);
  const int  srcI = slz - zb;

  // c^2*dt^2/dh^2 for the ext region — registers for the whole kernel.
  const bool xok = (unsigned)gx < (unsigned)NX;
  float c2[RPT];
  #pragma unroll
  for (int i = 0; i < RPT; ++i) {
    const int gz = gz0 + zb + i;
    const bool ok = xok && ((unsigned)gz < (unsigned)NZ);
    float v = ok ? vp[gz * NX + gx] : 0.0f;
    v *= DTf;
    c2[i] = v * v * INVDH2;
  }

  float a[RPT], b[RPT];   // a = newest level, b = previous level
  #pragma unroll
  for (int i = 0; i < RPT; ++i) { a[i] = 0.0f; b[i] = 0.0f; }

  const bool wbRow = (w >= 2 && w < 6) && (lane >= KSTEPS && lane < KSTEPS + TILE);
  const int  ilz   = (w - 2) * RPT;
  const int  ilx   = lane - KSTEPS;

  for (int ph = 0; ph < NPHASE; ++ph) {
    const int t0 = ph * KSTEPS;

    // Reload ext region from the pair written by the previous phase.
    if (ph > 0) {
      const float* ic = (ph & 1) ? f0c : f1c;
      const float* ip = (ph & 1) ? f0p : f1p;
      #pragma unroll
      for (int i = 0; i < RPT; ++i) {
        const int gz = gz0 + zb + i;
        const bool ok = xok && ((unsigned)gz < (unsigned)NZ);
        const int fidx = (s * NZ + gz) * NX + gx;
        a[i] = ok ? ic[fidx] : 0.0f;
        b[i] = ok ? ip[fidx] : 0.0f;
      }
    }

    float amp[KSTEPS];
    #pragma unroll
    for (int t = 0; t < KSTEPS; ++t)
      amp[t] = (xwav[s * NT + t0 + t] * DTf) * DTf;

    // One step: single __syncthreads (double-buffered halo + recTile;
    // receiver gather for step tau-1 is deferred into step tau).
    auto do_step = [&](float (&cur)[RPT], float (&nxt)[RPT], int tau) {
      const int pb = tau & 1;
      haloTop[pb][w][lane] = cur[0];
      haloBot[pb][w][lane] = cur[RPT - 1];
      __syncthreads();
      if (tau > 0 && tid < nRec) {
        out[(s * NT + (t0 + tau - 1)) * NRECS + recR[tid]] =
            recTile[1 - pb][recZL[tid]][recXL[tid]];
      }
      const float up0 = (w > 0)          ? haloBot[pb][w - 1][lane] : 0.0f;
      const float dn7 = (w < NWAVES - 1) ? haloTop[pb][w + 1][lane] : 0.0f;
      #pragma unroll
      for (int i = 0; i < RPT; ++i) {
        const float c  = cur[i];
        const float up = (i == 0)       ? up0 : cur[i - 1];
        const float dn = (i == RPT - 1) ? dn7 : cur[i + 1];
        const float lf = nbr_left(c);
        const float rt = nbr_right(c);
        const float sum = (up + dn) + (lf + rt);
        const float lap = __builtin_fmaf(-4.0f, c, sum);
        float v = __builtin_fmaf(2.0f, c, -nxt[i]);
        v = __builtin_fmaf(c2[i], lap, v);
        if (srcMine && i == srcI) v += amp[tau];
        nxt[i] = v;
      }
      if (wbRow) {
        #pragma unroll
        for (int i = 0; i < RPT; ++i)
          recTile[pb][ilz + i][ilx] = nxt[i];
      }
    };

    #pragma unroll
    for (int h = 0; h < KSTEPS / 2; ++h) {
      do_step(a, b, 2 * h);
      do_step(b, a, 2 * h + 1);
    }

    // Write back interior of the final two time levels (a=S16, b=S15).
    {
      float* oc = (ph & 1) ? f1c : f0c;
      float* op = (ph & 1) ? f1p : f0p;
      if (wbRow) {
        #pragma unroll
        for (int i = 0; i < RPT; ++i) {
          const int gz = gz0 + zb + i;
          const int fidx = (s * NZ + gz) * NX + gx;
          oc[fidx] = a[i];
          op[fidx] = b[i];
        }
      }
    }
    __syncthreads();               // recTile[1] complete + writeback stores drained
    if (tid < nRec) {
      out[(s * NT + (t0 + KSTEPS - 1)) * NRECS + recR[tid]] =
          recTile[1][recZL[tid]][recXL[tid]];
    }

    // Device-scope grid barrier between phases.
    if (ph != NPHASE - 1) {
      if (tid == 0) {
        __hip_atomic_fetch_add(ctr, 1u, __ATOMIC_RELEASE, __HIP_MEMORY_SCOPE_AGENT);
        const unsigned target = (unsigned)NWG * (unsigned)(ph + 1);
        while (__hip_atomic_load(ctr, __ATOMIC_ACQUIRE, __HIP_MEMORY_SCOPE_AGENT) < target)
          __builtin_amdgcn_s_sleep(2);
      }
      __syncthreads();
    }
  }
}

extern "C" void kernel_launch(void* const* d_in, const int* in_sizes, int n_in,
                              void* d_out, int out_size, void* d_ws, size_t ws_size,
                              hipStream_t stream) {
  const float* x     = (const float*)d_in[0];
  const float* vp    = (const float*)d_in[1];
  const int*   src_z = (const int*)d_in[2];
  const int*   src_x = (const int*)d_in[3];
  const int*   rec_z = (const int*)d_in[4];
  const int*   rec_x = (const int*)d_in[5];
  float* out = (float*)d_out;

  float* ws = (float*)d_ws;
  const size_t F = (size_t)NSHOTS * NZ * NX;
  float* f0c = ws;
  float* f0p = ws + F;
  float* f1c = ws + 2 * F;
  float* f1p = ws + 3 * F;
  unsigned* ctr = (unsigned*)(ws + 4 * F);

  // Only the barrier counter needs initialization (phase 0 starts from
  // in-register zeros; pair fields are fully written before first read).
  hipMemsetAsync(ctr, 0, sizeof(unsigned), stream);

  wave_all<<<dim3(NWG), dim3(BLOCK), 0, stream>>>(
      f0c, f0p, f1c, f1p, vp, x, src_z, src_x, rec_z, rec_x, out, ctr);
}

// Round 3
// 502.191 us; speedup vs baseline: 1.5632x; 1.5632x over previous
//
#include <hip/hip_runtime.h>

#define NSHOTS 4
#define NT     512
#define NZ     256
#define NX     256
#define NRECS  128

static constexpr float DTf    = 0.001f;
static constexpr float INVDH2 = 1.0f / (10.0f * 10.0f);

#define KSTEPS 16                 // fused time steps per launch
#define TILE   32                 // interior tile edge
#define RPT    8                  // ext rows per thread
#define NWAVES 8
#define BLOCK  512
#define NWG    (NSHOTS * 64)      // 256 workgroups, 1 per CU

// lane i <- lane i-1 (left x-neighbor); lane 0 gets 0 (matches zero pad)
__device__ __forceinline__ float nbr_left(float v) {
  return __int_as_float(__builtin_amdgcn_update_dpp(
      0, __float_as_int(v), 0x138 /*WAVE_SHR1*/, 0xf, 0xf, false));
}
// lane i <- lane i+1 (right x-neighbor); lane 63 gets 0
__device__ __forceinline__ float nbr_right(float v) {
  return __int_as_float(__builtin_amdgcn_update_dpp(
      0, __float_as_int(v), 0x130 /*WAVE_SHL1*/, 0xf, 0xf, false));
}

// Once per call: per-tile receiver compaction + per-thread receiver-cell masks.
__global__ __launch_bounds__(BLOCK) void precomp(
    const int* __restrict__ rec_z, const int* __restrict__ rec_x,
    int* __restrict__ nRecTab, unsigned* __restrict__ packTab,
    unsigned char* __restrict__ maskTab)
{
  const int bid = blockIdx.x;
  const int s = bid >> 6, tz = (bid >> 3) & 7, tx = bid & 7;
  const int tid = threadIdx.x;
  __shared__ int cnt;
  if (tid == 0) cnt = 0;
  __syncthreads();
  if (tid < NRECS) {
    const int lz = rec_z[s * NRECS + tid] - tz * TILE;
    const int lx = rec_x[s * NRECS + tid] - tx * TILE;
    if ((unsigned)lz < (unsigned)TILE && (unsigned)lx < (unsigned)TILE) {
      const int k = atomicAdd(&cnt, 1);
      packTab[bid * NRECS + k] = (unsigned)tid | ((unsigned)lz << 8) | ((unsigned)lx << 16);
    }
  }
  __syncthreads();
  if (tid == 0) nRecTab[bid] = cnt;

  const int w = tid >> 6, lane = tid & 63;
  unsigned m = 0;
  if (w >= 2 && w < 6 && lane >= KSTEPS && lane < KSTEPS + TILE) {
    const int ilz = (w - 2) * RPT, ilx = lane - KSTEPS;
    for (int r = 0; r < NRECS; ++r) {
      const int lz = rec_z[s * NRECS + r] - tz * TILE;
      const int lx = rec_x[s * NRECS + r] - tx * TILE;
      if (lx == ilx && (unsigned)(lz - ilz) < (unsigned)RPT) m |= 1u << (lz - ilz);
    }
  }
  maskTab[bid * BLOCK + tid] = (unsigned char)m;
}

// One launch = KSTEPS fused steps on a ghost-extended 64x64 region in registers.
__global__ __launch_bounds__(BLOCK, 2) void step16(
    const float* __restrict__ inCur, const float* __restrict__ inPrv,
    float* __restrict__ outCur, float* __restrict__ outPrv,
    const float* __restrict__ vp,
    const float* __restrict__ xwav,
    const int* __restrict__ src_z, const int* __restrict__ src_x,
    const int* __restrict__ nRecTab, const unsigned* __restrict__ packTab,
    const unsigned char* __restrict__ maskTab,
    float* __restrict__ out,
    int t0)
{
  const int bid  = blockIdx.x;
  const int s    = bid >> 6;
  const int tz   = (bid >> 3) & 7;
  const int tx   = bid & 7;
  const int tid  = threadIdx.x;
  const int w    = tid >> 6;
  const int lane = tid & 63;

  const int gz0 = tz * TILE - KSTEPS;
  const int gx0 = tx * TILE - KSTEPS;
  const int gx  = gx0 + lane;
  const int zb  = w * RPT;

  __shared__ float haloTop[2][NWAVES][64];
  __shared__ float haloBot[2][NWAVES][64];
  __shared__ float recTile[2][TILE][TILE + 1];

  // Precompacted receiver list (registers; same thread reads every step).
  const int nRec = nRecTab[bid];
  int myR = 0, myLz = 0, myLx = 0;
  if (tid < nRec) {
    const unsigned p = packTab[bid * NRECS + tid];
    myR = p & 255; myLz = (p >> 8) & 31; myLx = (p >> 16) & 31;
  }
  const unsigned recMask = maskTab[bid * BLOCK + tid];

  // Branchless source mask (ext-region coverage keeps halo values valid).
  const int slz = src_z[s] - gz0;
  const int slx = src_x[s] - gx0;
  const bool srcMine = (slx == lane) && ((unsigned)(slz - zb) < (unsigned)RPT);
  const int  srcI = slz - zb;
  float srcM[RPT];
  #pragma unroll
  for (int i = 0; i < RPT; ++i) srcM[i] = (srcMine && srcI == i) ? 1.0f : 0.0f;

  const bool xok = (unsigned)gx < (unsigned)NX;
  float a[RPT], b[RPT], c2[RPT];
  #pragma unroll
  for (int i = 0; i < RPT; ++i) {
    const int gz = gz0 + zb + i;
    const bool ok = xok && ((unsigned)gz < (unsigned)NZ);
    float v = ok ? vp[gz * NX + gx] : 0.0f;
    v *= DTf;
    c2[i] = v * v * INVDH2;
    if (t0 != 0) {
      const int fidx = (s * NZ + gz) * NX + gx;
      a[i] = ok ? inCur[fidx] : 0.0f;
      b[i] = ok ? inPrv[fidx] : 0.0f;
    } else {
      a[i] = 0.0f; b[i] = 0.0f;
    }
  }

  float amp[KSTEPS];
  #pragma unroll
  for (int t = 0; t < KSTEPS; ++t)
    amp[t] = (xwav[s * NT + t0 + t] * DTf) * DTf;

  const bool wbRow = (w >= 2 && w < 6) && (lane >= KSTEPS && lane < KSTEPS + TILE);
  const int  ilz   = (w - 2) * RPT;
  const int  ilx   = lane - KSTEPS;

  auto do_step = [&](float (&cur)[RPT], float (&nxt)[RPT], int tau) {
    const int pb = tau & 1;
    haloTop[pb][w][lane] = cur[0];
    haloBot[pb][w][lane] = cur[RPT - 1];
    __syncthreads();
    if (tau > 0 && tid < nRec) {
      out[(s * NT + (t0 + tau - 1)) * NRECS + myR] = recTile[1 - pb][myLz][myLx];
    }
    const float up0 = (w > 0)          ? haloBot[pb][w - 1][lane] : 0.0f;
    const float dn7 = (w < NWAVES - 1) ? haloTop[pb][w + 1][lane] : 0.0f;
    #pragma unroll
    for (int i = 0; i < RPT; ++i) {
      const float c  = cur[i];
      const float up = (i == 0)       ? up0 : cur[i - 1];
      const float dn = (i == RPT - 1) ? dn7 : cur[i + 1];
      const float lf = nbr_left(c);
      const float rt = nbr_right(c);
      const float sum = (up + dn) + (lf + rt);
      const float lap = __builtin_fmaf(-4.0f, c, sum);
      float v = __builtin_fmaf(2.0f, c, -nxt[i]);
      v = __builtin_fmaf(c2[i], lap, v);
      v = __builtin_fmaf(srcM[i], amp[tau], v);
      nxt[i] = v;
    }
    // Write only receiver cells (execz-skipped by ~all waves).
    if (recMask) {
      #pragma unroll
      for (int i = 0; i < RPT; ++i)
        if (recMask & (1u << i)) recTile[pb][ilz + i][ilx] = nxt[i];
    }
  };

  #pragma unroll
  for (int h = 0; h < KSTEPS / 2; ++h) {
    do_step(a, b, 2 * h);
    do_step(b, a, 2 * h + 1);
  }

  // Interior writeback of the final two time levels (a=S16, b=S15).
  if (wbRow) {
    #pragma unroll
    for (int i = 0; i < RPT; ++i) {
      const int gz = gz0 + zb + i;
      const int fidx = (s * NZ + gz) * NX + gx;
      outCur[fidx] = a[i];
      outPrv[fidx] = b[i];
    }
  }
  __syncthreads();
  if (tid < nRec) {
    out[(s * NT + (t0 + KSTEPS - 1)) * NRECS + myR] = recTile[1][myLz][myLx];
  }
}

extern "C" void kernel_launch(void* const* d_in, const int* in_sizes, int n_in,
                              void* d_out, int out_size, void* d_ws, size_t ws_size,
                              hipStream_t stream) {
  const float* x     = (const float*)d_in[0];
  const float* vp    = (const float*)d_in[1];
  const int*   src_z = (const int*)d_in[2];
  const int*   src_x = (const int*)d_in[3];
  const int*   rec_z = (const int*)d_in[4];
  const int*   rec_x = (const int*)d_in[5];
  float* out = (float*)d_out;

  float* ws = (float*)d_ws;
  const size_t F = (size_t)NSHOTS * NZ * NX;
  float* f0c = ws;
  float* f0p = ws + F;
  float* f1c = ws + 2 * F;
  float* f1p = ws + 3 * F;
  int*           nRecTab = (int*)(ws + 4 * F);
  unsigned*      packTab = (unsigned*)(nRecTab + NWG);
  unsigned char* maskTab = (unsigned char*)(packTab + (size_t)NWG * NRECS);

  precomp<<<dim3(NWG), dim3(BLOCK), 0, stream>>>(rec_z, rec_x, nRecTab, packTab, maskTab);

  for (int j = 0; j < NT / KSTEPS; ++j) {
    const float* ic = (j & 1) ? f1c : f0c;   // j==0: unused (t0==0 zero-init)
    const float* ip = (j & 1) ? f1p : f0p;
    float* oc = (j & 1) ? f0c : f1c;
    float* op = (j & 1) ? f0p : f1p;
    step16<<<dim3(NWG), dim3(BLOCK), 0, stream>>>(
        ic, ip, oc, op, vp, x, src_z, src_x,
        nRecTab, packTab, maskTab, out, j * KSTEPS);
  }
}

// Round 4
// 433.117 us; speedup vs baseline: 1.8125x; 1.1595x over previous
//
#include <hip/hip_runtime.h>

#define NSHOTS 4
#define NT     512
#define NZ     256
#define NX     256
#define NRECS  128

static constexpr float DTf    = 0.001f;
static constexpr float INVDH2 = 1.0f / (10.0f * 10.0f);

#define KSTEPS 16                 // fused steps per phase
#define TILE   32                 // interior tile edge
#define RPT    8                  // ext rows per thread
#define NWAVES 8
#define BLOCK  512
#define NWG    (NSHOTS * 64)      // 256 WGs, one per CU (co-resident)
#define NPHASE (NT / KSTEPS)      // 32
#define NLEAF  16                 // barrier tree fan-in
#define LSTRIDE 32                // dwords between counters (128 B)

// lane i <- lane i-1 (left x-neighbor); lane 0 gets 0 (matches zero pad)
__device__ __forceinline__ float nbr_left(float v) {
  return __int_as_float(__builtin_amdgcn_update_dpp(
      0, __float_as_int(v), 0x138 /*WAVE_SHR1*/, 0xf, 0xf, false));
}
// lane i <- lane i+1 (right x-neighbor); lane 63 gets 0
__device__ __forceinline__ float nbr_right(float v) {
  return __int_as_float(__builtin_amdgcn_update_dpp(
      0, __float_as_int(v), 0x130 /*WAVE_SHL1*/, 0xf, 0xf, false));
}

// LLC-coherent (cross-XCD) field access: agent-scope relaxed -> sc0 sc1,
// bypasses the non-coherent per-XCD L2s. No fences needed anywhere.
__device__ __forceinline__ float gload(const float* p) {
  return __hip_atomic_load(p, __ATOMIC_RELAXED, __HIP_MEMORY_SCOPE_AGENT);
}
__device__ __forceinline__ void gstore(float* p, float v) {
  __hip_atomic_store(p, v, __ATOMIC_RELAXED, __HIP_MEMORY_SCOPE_AGENT);
}

__global__ __launch_bounds__(BLOCK, 4) void wave_persist(
    float* __restrict__ f0c, float* __restrict__ f0p,   // pair 0 (written on even phases)
    float* __restrict__ f1c, float* __restrict__ f1p,   // pair 1 (written on odd phases)
    const float* __restrict__ vp, const float* __restrict__ xwav,
    const int* __restrict__ src_z, const int* __restrict__ src_x,
    const int* __restrict__ rec_z, const int* __restrict__ rec_x,
    float* __restrict__ out,                            // [NSHOTS*NT*NRECS]
    unsigned* __restrict__ bar)                         // [0]=root, leaves at 128B stride
{
  const int bid  = blockIdx.x;
  const int s    = bid >> 6;
  const int tz   = (bid >> 3) & 7;
  const int tx   = bid & 7;
  const int tid  = threadIdx.x;
  const int w    = tid >> 6;
  const int lane = tid & 63;

  const int gz0 = tz * TILE - KSTEPS;
  const int gx0 = tx * TILE - KSTEPS;
  const int gx  = gx0 + lane;
  const int zb  = w * RPT;

  __shared__ float haloTop[2][NWAVES][64];
  __shared__ float haloBot[2][NWAVES][64];
  __shared__ float recTile[2][TILE][TILE + 1];
  __shared__ int   cntS;
  __shared__ int   lzA[NRECS], lxA[NRECS];
  __shared__ unsigned pkA[NRECS];

  // ---- one-time prologue: receiver compaction + per-thread masks ----
  if (tid == 0) cntS = 0;
  __syncthreads();
  if (tid < NRECS) {
    const int lz = rec_z[s * NRECS + tid] - tz * TILE;
    const int lx = rec_x[s * NRECS + tid] - tx * TILE;
    lzA[tid] = lz; lxA[tid] = lx;
    if ((unsigned)lz < (unsigned)TILE && (unsigned)lx < (unsigned)TILE) {
      const int k = atomicAdd(&cntS, 1);
      pkA[k] = (unsigned)tid | ((unsigned)lz << 8) | ((unsigned)lx << 16);
    }
  }
  __syncthreads();
  const int nRec = cntS;
  int myR = 0, myLz = 0, myLx = 0;
  if (tid < nRec) {
    const unsigned p = pkA[tid];
    myR = p & 255; myLz = (p >> 8) & 31; myLx = (p >> 16) & 31;
  }
  const bool wbRow = (w >= 2 && w < 6) && (lane >= KSTEPS && lane < KSTEPS + TILE);
  const int  ilz   = (w - 2) * RPT;
  const int  ilx   = lane - KSTEPS;
  unsigned recMask = 0;
  if (wbRow) {
    for (int r = 0; r < NRECS; ++r)
      if (lxA[r] == ilx && (unsigned)(lzA[r] - ilz) < (unsigned)RPT)
        recMask |= 1u << (lzA[r] - ilz);
  }

  // source mask (ext-region coverage keeps halo values valid)
  const int slz = src_z[s] - gz0;
  const int slx = src_x[s] - gx0;
  const bool srcMine = (slx == lane) && ((unsigned)(slz - zb) < (unsigned)RPT);
  const int  srcI = slz - zb;
  float srcM[RPT];
  #pragma unroll
  for (int i = 0; i < RPT; ++i) srcM[i] = (srcMine && srcI == i) ? 1.0f : 0.0f;

  // c2 in registers for the whole kernel; fields start at exact zero
  const bool xok = (unsigned)gx < (unsigned)NX;
  float a[RPT], b[RPT], c2[RPT];
  #pragma unroll
  for (int i = 0; i < RPT; ++i) {
    const int gz = gz0 + zb + i;
    const bool ok = xok && ((unsigned)gz < (unsigned)NZ);
    float v = ok ? vp[gz * NX + gx] : 0.0f;
    v *= DTf;
    c2[i] = v * v * INVDH2;
    a[i] = 0.0f; b[i] = 0.0f;
  }

  #pragma unroll 1
  for (int ph = 0; ph < NPHASE; ++ph) {
    const int t0 = ph * KSTEPS;

    // reload ghost-extended region from the pair written last phase (LLC)
    if (ph > 0) {
      const float* rc = (ph & 1) ? f0c : f1c;
      const float* rp = (ph & 1) ? f0p : f1p;
      #pragma unroll
      for (int i = 0; i < RPT; ++i) {
        const int gz = gz0 + zb + i;
        const bool ok = xok && ((unsigned)gz < (unsigned)NZ);
        const int fidx = (s * NZ + gz) * NX + gx;
        a[i] = ok ? gload(rc + fidx) : 0.0f;
        b[i] = ok ? gload(rp + fidx) : 0.0f;
      }
    }

    float amp[KSTEPS];
    #pragma unroll
    for (int t = 0; t < KSTEPS; ++t)
      amp[t] = (xwav[s * NT + t0 + t] * DTf) * DTf;

    float recv[KSTEPS];   // receiver samples for this phase, registers only

    auto do_step = [&](float (&cur)[RPT], float (&nxt)[RPT], int tau) {
      const int pb = tau & 1;
      haloTop[pb][w][lane] = cur[0];
      haloBot[pb][w][lane] = cur[RPT - 1];
      __syncthreads();
      if (tau > 0 && tid < nRec) recv[tau - 1] = recTile[1 - pb][myLz][myLx];
      const float up0 = (w > 0)          ? haloBot[pb][w - 1][lane] : 0.0f;
      const float dn7 = (w < NWAVES - 1) ? haloTop[pb][w + 1][lane] : 0.0f;
      #pragma unroll
      for (int i = 0; i < RPT; ++i) {
        const float c  = cur[i];
        const float up = (i == 0)       ? up0 : cur[i - 1];
        const float dn = (i == RPT - 1) ? dn7 : cur[i + 1];
        const float lf = nbr_left(c);
        const float rt = nbr_right(c);
        const float sum = (up + dn) + (lf + rt);
        const float lap = __builtin_fmaf(-4.0f, c, sum);
        float v = __builtin_fmaf(2.0f, c, -nxt[i]);
        v = __builtin_fmaf(c2[i], lap, v);
        v = __builtin_fmaf(srcM[i], amp[tau], v);
        nxt[i] = v;
      }
      if (recMask) {
        #pragma unroll
        for (int i = 0; i < RPT; ++i)
          if (recMask & (1u << i)) recTile[pb][ilz + i][ilx] = nxt[i];
      }
    };

    #pragma unroll
    for (int h = 0; h < KSTEPS / 2; ++h) {
      do_step(a, b, 2 * h);
      do_step(b, a, 2 * h + 1);
    }

    __syncthreads();
    if (tid < nRec) recv[KSTEPS - 1] = recTile[1][myLz][myLx];

    // interior writeback (LLC-coherent) + receiver flush (plain stores)
    {
      float* wc = (ph & 1) ? f1c : f0c;
      float* wp = (ph & 1) ? f1p : f0p;
      if (wbRow) {
        #pragma unroll
        for (int i = 0; i < RPT; ++i) {
          const int gz = gz0 + zb + i;
          const int fidx = (s * NZ + gz) * NX + gx;
          gstore(wc + fidx, a[i]);
          gstore(wp + fidx, b[i]);
        }
      }
      if (tid < nRec) {
        #pragma unroll
        for (int t = 0; t < KSTEPS; ++t)
          out[(s * NT + (t0 + t)) * NRECS + myR] = recv[t];
      }
    }

    // flush-free grid barrier: per-wave drain, then 2-level relaxed counters
    if (ph != NPHASE - 1) {
      __builtin_amdgcn_s_waitcnt(0);     // all my stores ack'd at LLC (per wave)
      __syncthreads();                   // whole WG drained
      if (tid == 0) {
        unsigned* leaf = bar + (size_t)LSTRIDE * (1 + (bid & (NLEAF - 1)));
        const unsigned old = __hip_atomic_fetch_add(
            leaf, 1u, __ATOMIC_RELAXED, __HIP_MEMORY_SCOPE_AGENT);
        if (old == (unsigned)((NWG / NLEAF) * (ph + 1)) - 1u)
          __hip_atomic_fetch_add(bar, 1u, __ATOMIC_RELAXED, __HIP_MEMORY_SCOPE_AGENT);
        const unsigned target = (unsigned)(NLEAF * (ph + 1));
        while (__hip_atomic_load(bar, __ATOMIC_RELAXED, __HIP_MEMORY_SCOPE_AGENT) < target)
          __builtin_amdgcn_s_sleep(1);
      }
      __syncthreads();
    }
  }
}

extern "C" void kernel_launch(void* const* d_in, const int* in_sizes, int n_in,
                              void* d_out, int out_size, void* d_ws, size_t ws_size,
                              hipStream_t stream) {
  const float* x     = (const float*)d_in[0];
  const float* vp    = (const float*)d_in[1];
  const int*   src_z = (const int*)d_in[2];
  const int*   src_x = (const int*)d_in[3];
  const int*   rec_z = (const int*)d_in[4];
  const int*   rec_x = (const int*)d_in[5];
  float* out = (float*)d_out;

  float* ws = (float*)d_ws;
  const size_t F = (size_t)NSHOTS * NZ * NX;
  float* f0c = ws;
  float* f0p = ws + F;
  float* f1c = ws + 2 * F;
  float* f1p = ws + 3 * F;
  unsigned* bar = (unsigned*)(ws + 4 * F);

  // zero the barrier counters only (fields are written before any read)
  hipMemsetAsync(bar, 0, (1 + NLEAF) * LSTRIDE * sizeof(unsigned), stream);

  wave_persist<<<dim3(NWG), dim3(BLOCK), 0, stream>>>(
      f0c, f0p, f1c, f1p, vp, x, src_z, src_x, rec_z, rec_x, out, bar);
}

// Round 5
// 366.738 us; speedup vs baseline: 2.1406x; 1.1810x over previous
//
#include <hip/hip_runtime.h>

#define NSHOTS 4
#define NT     512
#define NZ     256
#define NX     256
#define NRECS  128

static constexpr float DTf    = 0.001f;
static constexpr float INVDH2 = 1.0f / (10.0f * 10.0f);

#define KSTEPS 16                 // fused steps per phase
#define TILE   32                 // interior tile edge
#define RPT    8                  // ext rows per thread
#define NWAVES 8
#define BLOCK  512
#define NWG    (NSHOTS * 64)      // 256 WGs, one per CU (co-resident)
#define NPHASE (NT / KSTEPS)      // 32
#define LSTRIDE 32                // dwords between flags (128 B)

// lane i <- lane i-1 (left x-neighbor); lane 0 gets 0 (matches zero pad)
__device__ __forceinline__ float nbr_left(float v) {
  return __int_as_float(__builtin_amdgcn_update_dpp(
      0, __float_as_int(v), 0x138 /*WAVE_SHR1*/, 0xf, 0xf, false));
}
// lane i <- lane i+1 (right x-neighbor); lane 63 gets 0
__device__ __forceinline__ float nbr_right(float v) {
  return __int_as_float(__builtin_amdgcn_update_dpp(
      0, __float_as_int(v), 0x130 /*WAVE_SHL1*/, 0xf, 0xf, false));
}

// LLC-coherent (cross-XCD) access: agent-scope relaxed -> sc0 sc1.
__device__ __forceinline__ float gload(const float* p) {
  return __hip_atomic_load(p, __ATOMIC_RELAXED, __HIP_MEMORY_SCOPE_AGENT);
}
__device__ __forceinline__ void gstore(float* p, float v) {
  __hip_atomic_store(p, v, __ATOMIC_RELAXED, __HIP_MEMORY_SCOPE_AGENT);
}
__device__ __forceinline__ unsigned fload(const unsigned* p) {
  return __hip_atomic_load(p, __ATOMIC_RELAXED, __HIP_MEMORY_SCOPE_AGENT);
}
__device__ __forceinline__ void fstore(unsigned* p, unsigned v) {
  __hip_atomic_store(p, v, __ATOMIC_RELAXED, __HIP_MEMORY_SCOPE_AGENT);
}

__global__ __launch_bounds__(BLOCK, 4) void wave_p2p(
    float* __restrict__ f0c, float* __restrict__ f0p,   // pair 0 (even-phase writes)
    float* __restrict__ f1c, float* __restrict__ f1p,   // pair 1 (odd-phase writes)
    const float* __restrict__ vp, const float* __restrict__ xwav,
    const int* __restrict__ src_z, const int* __restrict__ src_x,
    const int* __restrict__ rec_z, const int* __restrict__ rec_x,
    float* __restrict__ out,                            // [NSHOTS*NT*NRECS]
    unsigned* __restrict__ bar)                         // wFlag[NWG], rFlag[NWG] @128B stride
{
  const int bid  = blockIdx.x;
  const int s    = bid >> 6;
  const int tz   = (bid >> 3) & 7;
  const int tx   = bid & 7;
  const int tid  = threadIdx.x;
  const int w    = tid >> 6;
  const int lane = tid & 63;

  const int gz0 = tz * TILE - KSTEPS;
  const int gx0 = tx * TILE - KSTEPS;
  const int gx  = gx0 + lane;
  const int zb  = w * RPT;

  __shared__ float haloTop[2][NWAVES][64];
  __shared__ float haloBot[2][NWAVES][64];
  __shared__ float recTile[2][TILE][TILE + 1];
  __shared__ int   cntS;
  __shared__ int   lzA[NRECS], lxA[NRECS];
  __shared__ unsigned pkA[NRECS];

  // ---- prologue: receiver compaction + masks ----
  if (tid == 0) cntS = 0;
  __syncthreads();
  if (tid < NRECS) {
    const int lz = rec_z[s * NRECS + tid] - tz * TILE;
    const int lx = rec_x[s * NRECS + tid] - tx * TILE;
    lzA[tid] = lz; lxA[tid] = lx;
    if ((unsigned)lz < (unsigned)TILE && (unsigned)lx < (unsigned)TILE) {
      const int k = atomicAdd(&cntS, 1);
      pkA[k] = (unsigned)tid | ((unsigned)lz << 8) | ((unsigned)lx << 16);
    }
  }
  __syncthreads();
  const int nRec = cntS;
  int myR = 0, myLz = 0, myLx = 0;
  if (tid < nRec) {
    const unsigned p = pkA[tid];
    myR = p & 255; myLz = (p >> 8) & 31; myLx = (p >> 16) & 31;
  }
  const bool wbRow = (w >= 2 && w < 6) && (lane >= KSTEPS && lane < KSTEPS + TILE);
  const int  ilz   = (w - 2) * RPT;
  const int  ilx   = lane - KSTEPS;
  unsigned recMask = 0;
  if (wbRow) {
    for (int r = 0; r < NRECS; ++r)
      if (lxA[r] == ilx && (unsigned)(lzA[r] - ilz) < (unsigned)RPT)
        recMask |= 1u << (lzA[r] - ilz);
  }

  // neighbor bid for flag lanes (tid<8 -> the 8 surrounding tiles, same shot)
  int nb = -1;
  if (tid < 8) {
    const int k  = (tid < 4) ? tid : tid + 1;   // skip center of 3x3
    const int dz = k / 3 - 1, dx = k % 3 - 1;
    const int qz = tz + dz, qx = tx + dx;
    if ((unsigned)qz < 8u && (unsigned)qx < 8u)
      nb = (s << 6) | (qz << 3) | qx;
  }
  unsigned* wF = bar;
  unsigned* rF = bar + (size_t)NWG * LSTRIDE;

  auto pollGE = [&](unsigned* base, unsigned target) {
    if (nb >= 0) {
      while (fload(base + (size_t)nb * LSTRIDE) < target)
        __builtin_amdgcn_s_sleep(1);
    }
  };

  // source mask
  const int slz = src_z[s] - gz0;
  const int slx = src_x[s] - gx0;
  const bool srcMine = (slx == lane) && ((unsigned)(slz - zb) < (unsigned)RPT);
  const int  srcI = slz - zb;
  float srcM[RPT];
  #pragma unroll
  for (int i = 0; i < RPT; ++i) srcM[i] = (srcMine && srcI == i) ? 1.0f : 0.0f;

  // c2 in registers; fields start at exact zero
  const bool xok = (unsigned)gx < (unsigned)NX;
  float a[RPT], b[RPT], c2[RPT];
  #pragma unroll
  for (int i = 0; i < RPT; ++i) {
    const int gz = gz0 + zb + i;
    const bool ok = xok && ((unsigned)gz < (unsigned)NZ);
    float v = ok ? vp[gz * NX + gx] : 0.0f;
    v *= DTf;
    c2[i] = v * v * INVDH2;
    a[i] = 0.0f; b[i] = 0.0f;
  }

  #pragma unroll 1
  for (int ph = 0; ph < NPHASE; ++ph) {
    const int t0 = ph * KSTEPS;

    if (ph > 0) {
      // wait: all 8 neighbors finished writeback of phase ph-1
      pollGE(wF, (unsigned)ph);
      __syncthreads();
      // reload ghost region (interior-holding threads keep a,b in registers)
      const float* rc = (ph & 1) ? f0c : f1c;
      const float* rp = (ph & 1) ? f0p : f1p;
      if (!wbRow) {
        #pragma unroll
        for (int i = 0; i < RPT; ++i) {
          const int gz = gz0 + zb + i;
          const bool ok = xok && ((unsigned)gz < (unsigned)NZ);
          const int fidx = (s * NZ + gz) * NX + gx;
          a[i] = ok ? gload(rc + fidx) : 0.0f;
          b[i] = ok ? gload(rp + fidx) : 0.0f;
        }
      }
      __builtin_amdgcn_s_waitcnt(0);     // my reload actually read memory
      __syncthreads();
      if (tid == 0) fstore(rF + (size_t)bid * LSTRIDE, (unsigned)ph);
    }

    float amp[KSTEPS];
    #pragma unroll
    for (int t = 0; t < KSTEPS; ++t)
      amp[t] = (xwav[s * NT + t0 + t] * DTf) * DTf;

    float recv[KSTEPS];

    auto do_step = [&](float (&cur)[RPT], float (&nxt)[RPT], int tau) {
      const int pb = tau & 1;
      haloTop[pb][w][lane] = cur[0];
      haloBot[pb][w][lane] = cur[RPT - 1];
      __syncthreads();
      if (tau > 0 && tid < nRec) recv[tau - 1] = recTile[1 - pb][myLz][myLx];
      const float up0 = (w > 0)          ? haloBot[pb][w - 1][lane] : 0.0f;
      const float dn7 = (w < NWAVES - 1) ? haloTop[pb][w + 1][lane] : 0.0f;
      #pragma unroll
      for (int i = 0; i < RPT; ++i) {
        const float c  = cur[i];
        const float up = (i == 0)       ? up0 : cur[i - 1];
        const float dn = (i == RPT - 1) ? dn7 : cur[i + 1];
        const float lf = nbr_left(c);
        const float rt = nbr_right(c);
        const float sum = (up + dn) + (lf + rt);
        const float lap = __builtin_fmaf(-4.0f, c, sum);
        float v = __builtin_fmaf(2.0f, c, -nxt[i]);
        v = __builtin_fmaf(c2[i], lap, v);
        v = __builtin_fmaf(srcM[i], amp[tau], v);
        nxt[i] = v;
      }
      if (recMask) {
        #pragma unroll
        for (int i = 0; i < RPT; ++i)
          if (recMask & (1u << i)) recTile[pb][ilz + i][ilx] = nxt[i];
      }
    };

    #pragma unroll
    for (int h = 0; h < KSTEPS / 2; ++h) {
      do_step(a, b, 2 * h);
      do_step(b, a, 2 * h + 1);
    }

    // wait: neighbors consumed the pair we're about to overwrite
    if (ph >= 2 && ph != NPHASE - 1) pollGE(rF, (unsigned)(ph - 1));
    __syncthreads();   // recTile[1] ready + overwrite permission WG-wide
    if (tid < nRec) recv[KSTEPS - 1] = recTile[1][myLz][myLx];

    // receiver flush (normal cached stores; read only after kernel end)
    if (tid < nRec) {
      #pragma unroll
      for (int t = 0; t < KSTEPS; ++t)
        out[(s * NT + (t0 + t)) * NRECS + myR] = recv[t];
    }

    if (ph != NPHASE - 1) {
      // interior writeback (LLC-coherent)
      float* wc = (ph & 1) ? f1c : f0c;
      float* wp = (ph & 1) ? f1p : f0p;
      if (wbRow) {
        #pragma unroll
        for (int i = 0; i < RPT; ++i) {
          const int gz = gz0 + zb + i;
          const int fidx = (s * NZ + gz) * NX + gx;
          gstore(wc + fidx, a[i]);
          gstore(wp + fidx, b[i]);
        }
      }
      __builtin_amdgcn_s_waitcnt(0);   // stores ack'd at LLC (per wave)
      __syncthreads();                 // whole WG drained
      if (tid == 0) fstore(wF + (size_t)bid * LSTRIDE, (unsigned)(ph + 1));
    }
  }
}

extern "C" void kernel_launch(void* const* d_in, const int* in_sizes, int n_in,
                              void* d_out, int out_size, void* d_ws, size_t ws_size,
                              hipStream_t stream) {
  const float* x     = (const float*)d_in[0];
  const float* vp    = (const float*)d_in[1];
  const int*   src_z = (const int*)d_in[2];
  const int*   src_x = (const int*)d_in[3];
  const int*   rec_z = (const int*)d_in[4];
  const int*   rec_x = (const int*)d_in[5];
  float* out = (float*)d_out;

  float* ws = (float*)d_ws;
  const size_t F = (size_t)NSHOTS * NZ * NX;
  float* f0c = ws;
  float* f0p = ws + F;
  float* f1c = ws + 2 * F;
  float* f1p = ws + 3 * F;
  unsigned* bar = (unsigned*)(ws + 4 * F);

  // zero the p2p flags (wFlag + rFlag, 128B-strided)
  hipMemsetAsync(bar, 0, 2 * (size_t)NWG * LSTRIDE * sizeof(unsigned), stream);

  wave_p2p<<<dim3(NWG), dim3(BLOCK), 0, stream>>>(
      f0c, f0p, f1c, f1p, vp, x, src_z, src_x, rec_z, rec_x, out, bar);
}